// Round 5
// baseline (376.193 us; speedup 1.0000x reference)
//
#include <hip/hip_runtime.h>

// ---------------------------------------------------------------------------
// MaskedAutoregressiveFlow (RealNVP coupling) fused kernel for gfx950. R5.
// B=16384 rows, F=64, CTX=128, HID=512, L=8 layers, NB=2 hidden blocks.
//
// R5 = R4 + amdgpu_waves_per_eu(4,4). Allocator heuristic discovered over
// R1-R4: it targets 2 blocks/CU IGNORING LDS (VGPR choice = 512/(2*waves/4):
// 256thr->236, 512thr->128, 1024thr->64), and __launch_bounds__'s 2nd arg
// only sets the RANGE MIN, so it never stopped the under-allocation. The
// exact-range attribute (min=max=4 waves/EU) pins the budget at 128 VGPRs;
// MT=4/NTW=2 (~95-110 live) fits -> no scratch spill (R4 leaked ~300 MB/launch
// of scratch traffic: WRITE 69.5 MB, FETCH 280 MB).
//  - 1024 threads/block = 16 waves = 4 waves/EU; LDS 145 KB -> 1 block/CU.
//  - Wave owns MT=4 m-tiles x NTW=2 n-tiles; 16 waves x 2 = 32 n-tiles, B
//    fragments cross L2 exactly once per block (2.6 GB total stream).
// ---------------------------------------------------------------------------

typedef short v8s __attribute__((ext_vector_type(8)));   // 8 x bf16
typedef float v4f __attribute__((ext_vector_type(4)));   // MFMA acc

#define BATCH 16384
#define NF    64
#define NCTX  128
#define NHID  512
#define NL    8

#define PST   68    // LDS p row stride in floats

// packed-weight element offsets (bf16 elements)
#define WIN_EPL   (160 * 512)                               // 81920 / layer
#define WH_EPB    (512 * 512)                               // 262144 / (layer,block)
#define WOUT_EPL  (512 * 64)                                // 32768 / layer
#define OFF_WIN   ((size_t)0)
#define OFF_WH    ((size_t)(8 * WIN_EPL))                   // 655360
#define OFF_WOUT  (OFF_WH + (size_t)(16 * WH_EPB))          // 4849664
#define TOT_PACK_ELEMS (OFF_WOUT + (size_t)(8 * WOUT_EPL))  // 5111808
#define NEED_WS   (TOT_PACK_ELEMS * 2)                      // 10,223,616 B

// fp32 -> bf16, round-to-nearest-even
__device__ __forceinline__ unsigned short f2b(float f) {
    union { float f; unsigned int u; } x; x.f = f;
    unsigned int r = x.u + 0x7FFFu + ((x.u >> 16) & 1u);
    return (unsigned short)(r >> 16);
}

// LDS h swizzle: element (row, col) at row*512 + ((col>>3) ^ s(row))*8 + (col&7),
// s(row) = (row ^ (row>>2)) & 7.
__device__ __forceinline__ int sw3(int row) { return ((row ^ (row >> 2)) & 7) << 3; }

// ---------------------------------------------------------------------------
// pack: fp32 -> bf16 into MFMA B-fragment order, DESTINATION-ordered.
// Thread f produces packed elements [f*8, f*8+8): one coalesced 16B store.
// frag index = (kc*NT + nt)*64 + lane; lane = q*16+n15; k = kc*32+q*8+j;
// n = nt*16+n15.
// ---------------------------------------------------------------------------
__global__ void pack_weights_kernel(const float* __restrict__ W_in,
                                    const float* __restrict__ W_h,
                                    const float* __restrict__ W_out,
                                    unsigned short* __restrict__ ws) {
    const int FIN  = 8 * (WIN_EPL / 8);    // 81920 frags
    const int FH   = 16 * (WH_EPB / 8);    // 524288 frags
    const int FOUT = 8 * (WOUT_EPL / 8);   // 32768 frags
    int f = blockIdx.x * blockDim.x + threadIdx.x;
    if (f >= FIN + FH + FOUT) return;

    const float* src;
    int kcnt, lane, NT, N;
    if (f < FIN) {
        int i = f / (WIN_EPL / 8), r = f - i * (WIN_EPL / 8);
        kcnt = r >> 6; lane = r & 63; NT = 32; N = 512;
        src = W_in + (size_t)i * WIN_EPL;
    } else if (f < FIN + FH) {
        int u = f - FIN;
        int ij = u >> 15, r = u & 32767;
        kcnt = r >> 6; lane = r & 63; NT = 32; N = 512;
        src = W_h + (size_t)ij * WH_EPB;
    } else {
        int u = f - FIN - FH;
        int i = u >> 12, r = u & 4095;
        kcnt = r >> 6; lane = r & 63; NT = 4; N = 64;
        src = W_out + (size_t)i * WOUT_EPL;
    }
    int kc = (NT == 32) ? (kcnt >> 5) : (kcnt >> 2);
    int nt = kcnt - kc * NT;
    int k0 = kc * 32 + (lane >> 4) * 8;
    int n  = nt * 16 + (lane & 15);
    v8s o;
#pragma unroll
    for (int j = 0; j < 8; ++j)
        o[j] = (short)f2b(src[(size_t)(k0 + j) * N + n]);
    *(v8s*)(ws + (size_t)f * 8) = o;
}

__device__ __forceinline__ v4f mfma_bf16(v8s a, v8s b, v4f c) {
    return __builtin_amdgcn_mfma_f32_16x16x32_bf16(a, b, c, 0, 0, 0);
}

// One GEMM sub-stage per wave:
// C rows [mtb..mtb+MT)x16, cols [ntb..ntb+NTW)x16 = act(A @ W + bias).
// A from swizzled LDS; RELU writes bf16 to swizzled LDS; else fp32 -> Pbuf.
template<int KC, int MT, int NTW, int NTtot, bool PACKED, bool RELU>
__device__ __forceinline__ void gemm_stage(
    const unsigned short* __restrict__ wpk,
    const float* __restrict__ wraw, int rawN,
    const float* __restrict__ bias,
    const unsigned short* __restrict__ Abuf,
    unsigned short* __restrict__ Obuf,
    float* __restrict__ Pbuf,
    int mtb, int ntb, int lane)
{
    const int quad = lane >> 4, l15 = lane & 15;
    v4f acc[MT][NTW];
#pragma unroll
    for (int mt = 0; mt < MT; ++mt)
#pragma unroll
        for (int t = 0; t < NTW; ++t) {
            acc[mt][t][0] = 0.f; acc[mt][t][1] = 0.f;
            acc[mt][t][2] = 0.f; acc[mt][t][3] = 0.f;
        }
    int abase[MT], aswz[MT];
#pragma unroll
    for (int mt = 0; mt < MT; ++mt) {
        int row = (mtb + mt) * 16 + l15;
        abase[mt] = row * 512;
        aswz[mt]  = sw3(row);
    }

    const unsigned short* bptr =
        PACKED ? wpk + (size_t)(ntb * 64 + lane) * 8 : (const unsigned short*)0;

#pragma unroll 4
    for (int kc = 0; kc < KC; ++kc) {
        v8s a[MT];
#pragma unroll
        for (int mt = 0; mt < MT; ++mt) {
            int coff = ((kc * 4 + quad) << 3) ^ aswz[mt];
            a[mt] = *(const v8s*)(Abuf + abase[mt] + coff);
        }
        v8s b[NTW];
#pragma unroll
        for (int t = 0; t < NTW; ++t) {
            if constexpr (PACKED) {
                b[t] = *(const v8s*)(bptr + (size_t)(kc * NTtot + t) * 512);
            } else {
                int k0 = kc * 32 + quad * 8;
                int n  = (ntb + t) * 16 + l15;
                v8s bb;
#pragma unroll
                for (int j = 0; j < 8; ++j)
                    bb[j] = (short)f2b(wraw[(size_t)(k0 + j) * rawN + n]);
                b[t] = bb;
            }
        }
#pragma unroll
        for (int mt = 0; mt < MT; ++mt)
#pragma unroll
            for (int t = 0; t < NTW; ++t)
                acc[mt][t] = mfma_bf16(a[mt], b[t], acc[mt][t]);
    }
    // epilogue: D layout col = lane&15, row = quad*4 + reg (per 16x16 tile)
#pragma unroll
    for (int t = 0; t < NTW; ++t) {
        int n = (ntb + t) * 16 + l15;
        float bv = bias[n];
        int nch = (n >> 3) << 3, nlo = n & 7;
#pragma unroll
        for (int mt = 0; mt < MT; ++mt) {
#pragma unroll
            for (int r = 0; r < 4; ++r) {
                int row = (mtb + mt) * 16 + quad * 4 + r;
                float v = acc[mt][t][r] + bv;
                if constexpr (RELU) {
                    v = v > 0.f ? v : 0.f;
                    Obuf[row * 512 + (nch ^ sw3(row)) + nlo] = f2b(v);
                } else {
                    Pbuf[row * PST + n] = v;
                }
            }
        }
    }
}

template<bool PACKED>
__global__
__attribute__((amdgpu_waves_per_eu(4, 4)))   // pin: exactly 4 waves/EU -> 128-VGPR budget
__launch_bounds__(1024)
void flow_kernel(
    const float* __restrict__ inputs,
    const float* __restrict__ ctx,
    const float* __restrict__ W_in,  const float* __restrict__ b_in,
    const float* __restrict__ W_h,   const float* __restrict__ b_h,
    const float* __restrict__ W_out, const float* __restrict__ b_out,
    const int*   __restrict__ perms,
    const unsigned short* __restrict__ wpk,
    float* __restrict__ out)
{
    __shared__ __align__(16) unsigned short hbuf0[64 * 512];  // 65,536 B
    __shared__ __align__(16) unsigned short hbuf1[64 * 512];  // 65,536 B
    __shared__ __align__(16) float xbuf[64 * NF];             // 16,384 B
    __shared__ int permsh[NF];

    float* pbuf    = (float*)hbuf0;   // p (64 x 64 fp32, stride PST) after G3
    float* scratch = (float*)hbuf1;   // permutation scratch

    const int tid  = threadIdx.x;
    const int wave = tid >> 6;        // 0..15
    const int lane = tid & 63;
    const int trow = tid >> 4;        // 0..63 : row owned in elementwise phases
    const int tq   = tid & 15;        // 0..15 : 1/16th of that row
    const int row0 = blockIdx.x * 64;

    // ---- load + clip x tile (1024 float4 / 1024 threads = 1 each)
    {
        const float4* in4 = (const float4*)(inputs + (size_t)row0 * NF);
        float4 v = in4[tid];
        v.x = fminf(fmaxf(v.x, -1.f), 1.f);
        v.y = fminf(fmaxf(v.y, -1.f), 1.f);
        v.z = fminf(fmaxf(v.z, -1.f), 1.f);
        v.w = fminf(fmaxf(v.w, -1.f), 1.f);
        ((float4*)xbuf)[tid] = v;
    }
    float ld_acc = 0.f;
    __syncthreads();

#pragma unroll 1
    for (int i = 0; i < NL; ++i) {
        const int par = i & 1;        // t_idx parity (even layer -> even cols)
        const int idp = par ^ 1;      // id_idx parity

        // ---- stage A0 = [id_split(32) | context(128)] bf16 into hbuf0
        //      16 threads/row: each writes 1 ctx chunk; threads 0-3 also
        //      write 1 id chunk (chunk = 8 bf16 = one swizzle unit).
        {
            const int s3 = sw3(trow);
            unsigned short* hrow = hbuf0 + trow * 512;

            const float* crow = ctx + (size_t)(row0 + trow) * NCTX + tq * 8;
            float4 f0 = ((const float4*)crow)[0];
            float4 f1 = ((const float4*)crow)[1];
            v8s ck;
            ck[0] = (short)f2b(f0.x); ck[1] = (short)f2b(f0.y);
            ck[2] = (short)f2b(f0.z); ck[3] = (short)f2b(f0.w);
            ck[4] = (short)f2b(f1.x); ck[5] = (short)f2b(f1.y);
            ck[6] = (short)f2b(f1.z); ck[7] = (short)f2b(f1.w);
            *(v8s*)(hrow + (((4 + tq) << 3) ^ s3)) = ck;

            if (tq < 4) {
                v8s idv;
#pragma unroll
                for (int j = 0; j < 8; ++j)
                    idv[j] = (short)f2b(xbuf[trow * NF + 2 * (tq * 8 + j) + idp]);
                *(v8s*)(hrow + ((tq << 3) ^ s3)) = idv;
            }
        }
        __syncthreads();

        // ---- G0: h = relu([id|ctx] @ W_in + b_in)   (K=160, N=512)
        gemm_stage<5, 4, 2, 32, PACKED, true>(
            PACKED ? wpk + OFF_WIN + (size_t)i * WIN_EPL : (const unsigned short*)0,
            W_in + (size_t)i * WIN_EPL, 512, b_in + i * 512,
            hbuf0, hbuf1, nullptr, 0, wave * 2, lane);
        __syncthreads();
        // ---- G1
        gemm_stage<16, 4, 2, 32, PACKED, true>(
            PACKED ? wpk + OFF_WH + (size_t)(i * 2 + 0) * WH_EPB : (const unsigned short*)0,
            W_h + (size_t)(i * 2 + 0) * WH_EPB, 512, b_h + (i * 2 + 0) * 512,
            hbuf1, hbuf0, nullptr, 0, wave * 2, lane);
        __syncthreads();
        // ---- G2
        gemm_stage<16, 4, 2, 32, PACKED, true>(
            PACKED ? wpk + OFF_WH + (size_t)(i * 2 + 1) * WH_EPB : (const unsigned short*)0,
            W_h + (size_t)(i * 2 + 1) * WH_EPB, 512, b_h + (i * 2 + 1) * 512,
            hbuf0, hbuf1, nullptr, 0, wave * 2, lane);
        __syncthreads();
        // ---- G3: p = h @ W_out + b_out  (N=64, fp32 into pbuf)
        //      16 waves x 1 tile: mtb = wave>>2, ntb = wave&3
        gemm_stage<16, 1, 1, 4, PACKED, false>(
            PACKED ? wpk + OFF_WOUT + (size_t)i * WOUT_EPL : (const unsigned short*)0,
            W_out + (size_t)i * WOUT_EPL, 64, b_out + i * 64,
            hbuf1, nullptr, pbuf, wave >> 2, wave & 3, lane);
        __syncthreads();

        // ---- coupling: shift = p[:, :32]; scale = sigmoid(p[:,32:]+2)+1e-3
        {
#pragma unroll
            for (int j = 0; j < 2; ++j) {
                int sc = tq * 2 + j;
                float shiftv = pbuf[trow * PST + sc];
                float z = pbuf[trow * PST + 32 + sc] + 2.0f;
                float s = 1.0f / (1.0f + __expf(-z)) + 0.001f;
                int tc = 2 * sc + par;
                xbuf[trow * NF + tc] = xbuf[trow * NF + tc] * s + shiftv;
                ld_acc += __logf(s);
            }
        }
        __syncthreads();

        // ---- permutation: x = x[:, perm[i]]
        if (i < NL - 1) {
            ((float4*)scratch)[tid] = ((float4*)xbuf)[tid];
            if (tid < NF) permsh[tid] = perms[i * NF + tid];
            __syncthreads();
#pragma unroll
            for (int j = 0; j < 4; ++j) {
                int c = tq * 4 + j;
                xbuf[trow * NF + c] = scratch[trow * NF + permsh[c]];
            }
            __syncthreads();
        }
    }

    // ---- outputs: clip(x) then logdet
    {
        float4 v = ((float4*)xbuf)[tid];
        v.x = fminf(fmaxf(v.x, -1.f), 1.f);
        v.y = fminf(fmaxf(v.y, -1.f), 1.f);
        v.z = fminf(fmaxf(v.z, -1.f), 1.f);
        v.w = fminf(fmaxf(v.w, -1.f), 1.f);
        ((float4*)(out + (size_t)row0 * NF))[tid] = v;
    }
    // reduce 16 partials per row (lanes 16r..16r+15 contiguous in a wave)
    ld_acc += __shfl_down(ld_acc, 1);
    ld_acc += __shfl_down(ld_acc, 2);
    ld_acc += __shfl_down(ld_acc, 4);
    ld_acc += __shfl_down(ld_acc, 8);
    if (tq == 0) out[(size_t)BATCH * NF + row0 + trow] = ld_acc;
}

extern "C" void kernel_launch(void* const* d_in, const int* in_sizes, int n_in,
                              void* d_out, int out_size, void* d_ws, size_t ws_size,
                              hipStream_t stream) {
    const float* inputs  = (const float*)d_in[0];
    const float* context = (const float*)d_in[1];
    const float* W_in    = (const float*)d_in[2];
    const float* b_in    = (const float*)d_in[3];
    const float* W_h     = (const float*)d_in[4];
    const float* b_h     = (const float*)d_in[5];
    const float* W_out   = (const float*)d_in[6];
    const float* b_out   = (const float*)d_in[7];
    const int*   perms   = (const int*)d_in[8];
    float* out = (float*)d_out;

    if (ws_size >= (size_t)NEED_WS) {
        unsigned short* ws = (unsigned short*)d_ws;
        const int total_frags = (int)(TOT_PACK_ELEMS / 8);      // 638976
        pack_weights_kernel<<<(total_frags + 255) / 256, 256, 0, stream>>>(
            W_in, W_h, W_out, ws);
        flow_kernel<true><<<256, 1024, 0, stream>>>(
            inputs, context, W_in, b_in, W_h, b_h, W_out, b_out, perms, ws, out);
    } else {
        flow_kernel<false><<<256, 1024, 0, stream>>>(
            inputs, context, W_in, b_in, W_h, b_h, W_out, b_out, perms,
            (const unsigned short*)0, out);
    }
}

// Round 6
// 344.692 us; speedup vs baseline: 1.0914x; 1.0914x over previous
//
#include <hip/hip_runtime.h>

// ---------------------------------------------------------------------------
// MaskedAutoregressiveFlow (RealNVP coupling) fused kernel for gfx950. R6.
// B=16384 rows, F=64, CTX=128, HID=512, L=8 layers, NB=2 hidden blocks.
//
// R6: stop fighting the register allocator (R3/R5 attributes ignored; it
// budgets 512/(2*waves_per_block/4) VGPRs = 64 @ 1024 thr, assuming 2
// blocks/CU despite 145 KB LDS). Restructure so 64 VGPRs SUFFICE:
//  - N=512 GEMMs use mfma_f32_32x32x16_bf16; wave owns 2 m-tiles (64 rows)
//    x 1 n-tile (32 cols). acc 32 + a 8 + b 4+4(prefetch) + addr ~15 <= 64.
//  - 16 waves x 32 cols = 512: every weight fragment read once per block
//    (L2 stream stays 2.6 GB).
//  - K-loop: no unroll + manual 1-deep B prefetch; 16 waves/CU of TLP
//    saturate L2 BW (~56 B/cyc/CU) without deep per-wave pipelining.
//  - G3 (N=64) keeps 16x16x32 path, MT=1/NTW=1 (tiny registers).
// Layouts (HW-verified per guide): 32x32x16 A/B: lane=(k>>3)*32+(m|n),
// elem=k&7; C/D: col=lane&31, row=(reg&3)+8*(reg>>2)+4*(lane>>5).
// ---------------------------------------------------------------------------

typedef short v8s  __attribute__((ext_vector_type(8)));   // 8 x bf16
typedef float v4f  __attribute__((ext_vector_type(4)));   // 16x16 acc
typedef float v16f __attribute__((ext_vector_type(16)));  // 32x32 acc

#define BATCH 16384
#define NF    64
#define NCTX  128
#define NL    8

#define PST   68    // LDS p row stride in floats

// packed-weight element offsets (bf16 elements)
#define WIN_EPL   (160 * 512)                               // 81920 / layer
#define WH_EPB    (512 * 512)                               // 262144 / (layer,block)
#define WOUT_EPL  (512 * 64)                                // 32768 / layer
#define OFF_WIN   ((size_t)0)
#define OFF_WH    ((size_t)(8 * WIN_EPL))                   // 655360
#define OFF_WOUT  (OFF_WH + (size_t)(16 * WH_EPB))          // 4849664
#define TOT_PACK_ELEMS (OFF_WOUT + (size_t)(8 * WOUT_EPL))  // 5111808
#define NEED_WS   (TOT_PACK_ELEMS * 2)                      // 10,223,616 B

// fp32 -> bf16, round-to-nearest-even
__device__ __forceinline__ unsigned short f2b(float f) {
    union { float f; unsigned int u; } x; x.f = f;
    unsigned int r = x.u + 0x7FFFu + ((x.u >> 16) & 1u);
    return (unsigned short)(r >> 16);
}

// LDS h swizzle: element (row, col) at row*512 + ((col>>3) ^ s(row))*8 + (col&7),
// s(row) = (row ^ (row>>2)) & 7.
__device__ __forceinline__ int sw3(int row) { return ((row ^ (row >> 2)) & 7) << 3; }

// ---------------------------------------------------------------------------
// pack: fp32 -> bf16, DESTINATION-ordered (one coalesced 16B store/thread).
// W_in/W_h -> 32x32x16 B-frag order: frag = kc*16 + nt (512 elems);
//   lane l: k = kc*16 + (l>>5)*8 + j, n = nt*32 + (l&31).
// W_out -> 16x16x32 B-frag order: frag = kc*4 + nt;
//   lane l: k = kc*32 + (l>>4)*8 + j, n = nt*16 + (l&15).
// ---------------------------------------------------------------------------
__global__ void pack_weights_kernel(const float* __restrict__ W_in,
                                    const float* __restrict__ W_h,
                                    const float* __restrict__ W_out,
                                    unsigned short* __restrict__ ws) {
    const int TIN  = 8 * (WIN_EPL / 8);     // 81920
    const int TH   = 16 * (WH_EPB / 8);     // 524288
    const int TOUT = 8 * (WOUT_EPL / 8);    // 32768
    int t = blockIdx.x * blockDim.x + threadIdx.x;
    if (t >= TIN + TH + TOUT) return;
    v8s o;
    if (t < TIN + TH) {
        const float* src; int r;
        if (t < TIN) {
            int i = t / (WIN_EPL / 8); r = t - i * (WIN_EPL / 8);
            src = W_in + (size_t)i * WIN_EPL;
        } else {
            int u = t - TIN; int ij = u >> 15; r = u & 32767;
            src = W_h + (size_t)ij * WH_EPB;
        }
        int frag = r >> 6, lane = r & 63;
        int k0 = (frag >> 4) * 16 + (lane >> 5) * 8;
        int n  = (frag & 15) * 32 + (lane & 31);
#pragma unroll
        for (int j = 0; j < 8; ++j)
            o[j] = (short)f2b(src[(size_t)(k0 + j) * 512 + n]);
    } else {
        int u = t - TIN - TH;
        int i = u >> 12, r = u & 4095;
        const float* src = W_out + (size_t)i * WOUT_EPL;
        int frag = r >> 6, lane = r & 63;
        int k0 = (frag >> 2) * 32 + (lane >> 4) * 8;
        int n  = (frag & 3) * 16 + (lane & 15);
#pragma unroll
        for (int j = 0; j < 8; ++j)
            o[j] = (short)f2b(src[(size_t)(k0 + j) * 64 + n]);
    }
    *(v8s*)(ws + (size_t)t * 8) = o;
}

// ---------------------------------------------------------------------------
// 32x32x16 stage: h' = relu(A[64,KC*16] @ W[.,512] + bias) for one 32-col
// strip (ntile). Wave covers both 32-row tiles -> B frags read exactly once.
// ---------------------------------------------------------------------------
template<int KC, bool PACKED>
__device__ __forceinline__ void gemm32(
    const unsigned short* __restrict__ wpk,
    const float* __restrict__ wraw,
    const float* __restrict__ bias,
    const unsigned short* __restrict__ Abuf,
    unsigned short* __restrict__ Obuf,
    int ntile, int lane)
{
    const int l31 = lane & 31, half = lane >> 5;
    v16f acc0, acc1;
#pragma unroll
    for (int r = 0; r < 16; ++r) { acc0[r] = 0.f; acc1[r] = 0.f; }
    const int row0 = l31, row1 = 32 + l31;
    const int ab0 = row0 * 512, ab1 = row1 * 512;
    const int sz0 = sw3(row0), sz1 = sw3(row1);
    const unsigned short* bptr =
        PACKED ? wpk + (size_t)(ntile * 64 + lane) * 8 : (const unsigned short*)0;

    // 1-deep B prefetch: load kc, compute kc-1.
    v8s bcur;
    if constexpr (PACKED) {
        bcur = *(const v8s*)(bptr);
    } else {
        int n = ntile * 32 + l31;
#pragma unroll
        for (int j = 0; j < 8; ++j)
            bcur[j] = (short)f2b(wraw[(size_t)(half * 8 + j) * 512 + n]);
    }
#pragma unroll 1
    for (int kc = 0; kc < KC; ++kc) {
        const int kcn = (kc + 1 < KC) ? kc + 1 : kc;
        v8s bnxt;
        if constexpr (PACKED) {
            bnxt = *(const v8s*)(bptr + (size_t)kcn * (16 * 512));
        } else {
            int n = ntile * 32 + l31;
            int k0 = kcn * 16 + half * 8;
#pragma unroll
            for (int j = 0; j < 8; ++j)
                bnxt[j] = (short)f2b(wraw[(size_t)(k0 + j) * 512 + n]);
        }
        const int cch = (kc * 2 + half) << 3;
        v8s a0 = *(const v8s*)(Abuf + ab0 + (cch ^ sz0));
        v8s a1 = *(const v8s*)(Abuf + ab1 + (cch ^ sz1));
        acc0 = __builtin_amdgcn_mfma_f32_32x32x16_bf16(a0, bcur, acc0, 0, 0, 0);
        acc1 = __builtin_amdgcn_mfma_f32_32x32x16_bf16(a1, bcur, acc1, 0, 0, 0);
        bcur = bnxt;
    }
    // epilogue: col = ntile*32 + (lane&31); row = (reg&3)+8*(reg>>2)+4*half
    const int n = ntile * 32 + l31;
    const float bv = bias[n];
    const int nch = (n >> 3) << 3, nlo = n & 7;
#pragma unroll
    for (int reg = 0; reg < 16; ++reg) {
        int row = (reg & 3) + 8 * (reg >> 2) + 4 * half;
        float v0 = acc0[reg] + bv; v0 = v0 > 0.f ? v0 : 0.f;
        Obuf[row * 512 + (nch ^ sw3(row)) + nlo] = f2b(v0);
        int rw1 = row + 32;
        float v1 = acc1[reg] + bv; v1 = v1 > 0.f ? v1 : 0.f;
        Obuf[rw1 * 512 + (nch ^ sw3(rw1)) + nlo] = f2b(v1);
    }
}

__device__ __forceinline__ v4f mfma16(v8s a, v8s b, v4f c) {
    return __builtin_amdgcn_mfma_f32_16x16x32_bf16(a, b, c, 0, 0, 0);
}

// 16x16x32 output stage (G3): p[16 rows x 16 cols] = h @ W_out + b_out, fp32.
template<bool PACKED>
__device__ __forceinline__ void gemm16_out(
    const unsigned short* __restrict__ wpk,
    const float* __restrict__ wraw,
    const float* __restrict__ bias,
    const unsigned short* __restrict__ Abuf,
    float* __restrict__ Pbuf,
    int mtb, int ntb, int lane)
{
    const int quad = lane >> 4, l15 = lane & 15;
    v4f acc; acc[0] = acc[1] = acc[2] = acc[3] = 0.f;
    const int row = mtb * 16 + l15;
    const int ab = row * 512, sz = sw3(row);
    const unsigned short* bptr =
        PACKED ? wpk + (size_t)(ntb * 64 + lane) * 8 : (const unsigned short*)0;
#pragma unroll 4
    for (int kc = 0; kc < 16; ++kc) {
        v8s a = *(const v8s*)(Abuf + ab + ((((kc * 4 + quad) << 3)) ^ sz));
        v8s b;
        if constexpr (PACKED) {
            b = *(const v8s*)(bptr + (size_t)(kc * 4) * 512);
        } else {
            int k0 = kc * 32 + quad * 8;
            int n  = ntb * 16 + l15;
#pragma unroll
            for (int j = 0; j < 8; ++j)
                b[j] = (short)f2b(wraw[(size_t)(k0 + j) * 64 + n]);
        }
        acc = mfma16(a, b, acc);
    }
    const int n = ntb * 16 + l15;
    const float bv = bias[n];
#pragma unroll
    for (int r = 0; r < 4; ++r)
        Pbuf[(mtb * 16 + quad * 4 + r) * PST + n] = acc[r] + bv;
}

template<bool PACKED>
__global__ __launch_bounds__(1024) void flow_kernel(
    const float* __restrict__ inputs,
    const float* __restrict__ ctx,
    const float* __restrict__ W_in,  const float* __restrict__ b_in,
    const float* __restrict__ W_h,   const float* __restrict__ b_h,
    const float* __restrict__ W_out, const float* __restrict__ b_out,
    const int*   __restrict__ perms,
    const unsigned short* __restrict__ wpk,
    float* __restrict__ out)
{
    __shared__ __align__(16) unsigned short hbuf0[64 * 512];  // 65,536 B
    __shared__ __align__(16) unsigned short hbuf1[64 * 512];  // 65,536 B
    __shared__ __align__(16) float xbuf[64 * NF];             // 16,384 B
    __shared__ int permsh[NF];

    float* pbuf    = (float*)hbuf0;   // p (64 x 64 fp32, stride PST) after G3
    float* scratch = (float*)hbuf1;   // permutation scratch

    const int tid  = threadIdx.x;
    const int wave = tid >> 6;        // 0..15
    const int lane = tid & 63;
    const int trow = tid >> 4;        // 0..63 : row owned in elementwise phases
    const int tq   = tid & 15;        // 0..15 : 1/16th of that row
    const int row0 = blockIdx.x * 64;

    // ---- load + clip x tile (1024 float4 / 1024 threads = 1 each)
    {
        const float4* in4 = (const float4*)(inputs + (size_t)row0 * NF);
        float4 v = in4[tid];
        v.x = fminf(fmaxf(v.x, -1.f), 1.f);
        v.y = fminf(fmaxf(v.y, -1.f), 1.f);
        v.z = fminf(fmaxf(v.z, -1.f), 1.f);
        v.w = fminf(fmaxf(v.w, -1.f), 1.f);
        ((float4*)xbuf)[tid] = v;
    }
    float ld_acc = 0.f;
    __syncthreads();

#pragma unroll 1
    for (int i = 0; i < NL; ++i) {
        const int par = i & 1;        // t_idx parity (even layer -> even cols)
        const int idp = par ^ 1;      // id_idx parity

        // ---- stage A0 = [id_split(32) | context(128)] bf16 into hbuf0
        {
            const int s3 = sw3(trow);
            unsigned short* hrow = hbuf0 + trow * 512;

            const float* crow = ctx + (size_t)(row0 + trow) * NCTX + tq * 8;
            float4 f0 = ((const float4*)crow)[0];
            float4 f1 = ((const float4*)crow)[1];
            v8s ck;
            ck[0] = (short)f2b(f0.x); ck[1] = (short)f2b(f0.y);
            ck[2] = (short)f2b(f0.z); ck[3] = (short)f2b(f0.w);
            ck[4] = (short)f2b(f1.x); ck[5] = (short)f2b(f1.y);
            ck[6] = (short)f2b(f1.z); ck[7] = (short)f2b(f1.w);
            *(v8s*)(hrow + (((4 + tq) << 3) ^ s3)) = ck;

            if (tq < 4) {
                v8s idv;
#pragma unroll
                for (int j = 0; j < 8; ++j)
                    idv[j] = (short)f2b(xbuf[trow * NF + 2 * (tq * 8 + j) + idp]);
                *(v8s*)(hrow + ((tq << 3) ^ s3)) = idv;
            }
        }
        __syncthreads();

        // ---- G0: h = relu([id|ctx] @ W_in + b_in)   (K=160, N=512)
        gemm32<10, PACKED>(
            PACKED ? wpk + OFF_WIN + (size_t)i * WIN_EPL : (const unsigned short*)0,
            W_in + (size_t)i * WIN_EPL, b_in + i * 512,
            hbuf0, hbuf1, wave, lane);
        __syncthreads();
        // ---- G1
        gemm32<32, PACKED>(
            PACKED ? wpk + OFF_WH + (size_t)(i * 2 + 0) * WH_EPB : (const unsigned short*)0,
            W_h + (size_t)(i * 2 + 0) * WH_EPB, b_h + (i * 2 + 0) * 512,
            hbuf1, hbuf0, wave, lane);
        __syncthreads();
        // ---- G2
        gemm32<32, PACKED>(
            PACKED ? wpk + OFF_WH + (size_t)(i * 2 + 1) * WH_EPB : (const unsigned short*)0,
            W_h + (size_t)(i * 2 + 1) * WH_EPB, b_h + (i * 2 + 1) * 512,
            hbuf0, hbuf1, wave, lane);
        __syncthreads();
        // ---- G3: p = h @ W_out + b_out  (N=64, fp32 into pbuf)
        //      16 waves x 1 tile: mtb = wave>>2, ntb = wave&3
        gemm16_out<PACKED>(
            PACKED ? wpk + OFF_WOUT + (size_t)i * WOUT_EPL : (const unsigned short*)0,
            W_out + (size_t)i * WOUT_EPL, b_out + i * 64,
            hbuf1, pbuf, wave >> 2, wave & 3, lane);
        __syncthreads();

        // ---- coupling: shift = p[:, :32]; scale = sigmoid(p[:,32:]+2)+1e-3
        {
#pragma unroll
            for (int j = 0; j < 2; ++j) {
                int sc = tq * 2 + j;
                float shiftv = pbuf[trow * PST + sc];
                float z = pbuf[trow * PST + 32 + sc] + 2.0f;
                float s = 1.0f / (1.0f + __expf(-z)) + 0.001f;
                int tc = 2 * sc + par;
                xbuf[trow * NF + tc] = xbuf[trow * NF + tc] * s + shiftv;
                ld_acc += __logf(s);
            }
        }
        __syncthreads();

        // ---- permutation: x = x[:, perm[i]]
        if (i < NL - 1) {
            ((float4*)scratch)[tid] = ((float4*)xbuf)[tid];
            if (tid < NF) permsh[tid] = perms[i * NF + tid];
            __syncthreads();
#pragma unroll
            for (int j = 0; j < 4; ++j) {
                int c = tq * 4 + j;
                xbuf[trow * NF + c] = scratch[trow * NF + permsh[c]];
            }
            __syncthreads();
        }
    }

    // ---- outputs: clip(x) then logdet
    {
        float4 v = ((float4*)xbuf)[tid];
        v.x = fminf(fmaxf(v.x, -1.f), 1.f);
        v.y = fminf(fmaxf(v.y, -1.f), 1.f);
        v.z = fminf(fmaxf(v.z, -1.f), 1.f);
        v.w = fminf(fmaxf(v.w, -1.f), 1.f);
        ((float4*)(out + (size_t)row0 * NF))[tid] = v;
    }
    // reduce 16 partials per row (lanes 16r..16r+15 contiguous in a wave)
    ld_acc += __shfl_down(ld_acc, 1);
    ld_acc += __shfl_down(ld_acc, 2);
    ld_acc += __shfl_down(ld_acc, 4);
    ld_acc += __shfl_down(ld_acc, 8);
    if (tq == 0) out[(size_t)BATCH * NF + row0 + trow] = ld_acc;
}

extern "C" void kernel_launch(void* const* d_in, const int* in_sizes, int n_in,
                              void* d_out, int out_size, void* d_ws, size_t ws_size,
                              hipStream_t stream) {
    const float* inputs  = (const float*)d_in[0];
    const float* context = (const float*)d_in[1];
    const float* W_in    = (const float*)d_in[2];
    const float* b_in    = (const float*)d_in[3];
    const float* W_h     = (const float*)d_in[4];
    const float* b_h     = (const float*)d_in[5];
    const float* W_out   = (const float*)d_in[6];
    const float* b_out   = (const float*)d_in[7];
    const int*   perms   = (const int*)d_in[8];
    float* out = (float*)d_out;

    if (ws_size >= (size_t)NEED_WS) {
        unsigned short* ws = (unsigned short*)d_ws;
        const int total_threads = (int)(TOT_PACK_ELEMS / 8);    // 638976
        pack_weights_kernel<<<(total_threads + 255) / 256, 256, 0, stream>>>(
            W_in, W_h, W_out, ws);
        flow_kernel<true><<<256, 1024, 0, stream>>>(
            inputs, context, W_in, b_in, W_h, b_h, W_out, b_out, perms, ws, out);
    } else {
        flow_kernel<false><<<256, 1024, 0, stream>>>(
            inputs, context, W_in, b_in, W_h, b_h, W_out, b_out, perms,
            (const unsigned short*)0, out);
    }
}

// Round 7
// 300.518 us; speedup vs baseline: 1.2518x; 1.1470x over previous
//
#include <hip/hip_runtime.h>

// ---------------------------------------------------------------------------
// MaskedAutoregressiveFlow (RealNVP coupling) fused kernel for gfx950. R7.
// B=16384 rows, F=64, CTX=128, HID=512, L=8 layers, NB=2 hidden blocks.
//
// R7 = R6 + 3-deep B prefetch pipeline. R6 killed the spills (WRITE 69.6->5.2
// MB) but the 1-deep prefetch serialized each wave to 1 outstanding 1KB
// B-load per ~200cyc L2 latency -> MfmaUtil 25.6% (matches 4 waves x 16
// MFMA-cyc / 200cyc). D=3 rotation keeps vmcnt(2) in the K-loop (AITER
// pattern): 16 waves x 3KB = 48KB outstanding/CU >> 11KB needed for L2 BW.
// Register budget (allocator pins 64 @ 1024thr): acc 32 + b 12 + a 8 + addr.
// ---------------------------------------------------------------------------

typedef short v8s  __attribute__((ext_vector_type(8)));   // 8 x bf16
typedef float v4f  __attribute__((ext_vector_type(4)));   // 16x16 acc
typedef float v16f __attribute__((ext_vector_type(16)));  // 32x32 acc

#define BATCH 16384
#define NF    64
#define NCTX  128
#define NL    8

#define PST   68    // LDS p row stride in floats

// packed-weight element offsets (bf16 elements)
#define WIN_EPL   (160 * 512)                               // 81920 / layer
#define WH_EPB    (512 * 512)                               // 262144 / (layer,block)
#define WOUT_EPL  (512 * 64)                                // 32768 / layer
#define OFF_WIN   ((size_t)0)
#define OFF_WH    ((size_t)(8 * WIN_EPL))                   // 655360
#define OFF_WOUT  (OFF_WH + (size_t)(16 * WH_EPB))          // 4849664
#define TOT_PACK_ELEMS (OFF_WOUT + (size_t)(8 * WOUT_EPL))  // 5111808
#define NEED_WS   (TOT_PACK_ELEMS * 2)                      // 10,223,616 B

// fp32 -> bf16, round-to-nearest-even
__device__ __forceinline__ unsigned short f2b(float f) {
    union { float f; unsigned int u; } x; x.f = f;
    unsigned int r = x.u + 0x7FFFu + ((x.u >> 16) & 1u);
    return (unsigned short)(r >> 16);
}

// LDS h swizzle: element (row, col) at row*512 + ((col>>3) ^ s(row))*8 + (col&7),
// s(row) = (row ^ (row>>2)) & 7.
__device__ __forceinline__ int sw3(int row) { return ((row ^ (row >> 2)) & 7) << 3; }

// ---------------------------------------------------------------------------
// pack: fp32 -> bf16, DESTINATION-ordered (one coalesced 16B store/thread).
// W_in/W_h -> 32x32x16 B-frag order: frag = kc*16 + nt (512 elems);
//   lane l: k = kc*16 + (l>>5)*8 + j, n = nt*32 + (l&31).
// W_out -> 16x16x32 B-frag order: frag = kc*4 + nt;
//   lane l: k = kc*32 + (l>>4)*8 + j, n = nt*16 + (l&15).
// ---------------------------------------------------------------------------
__global__ void pack_weights_kernel(const float* __restrict__ W_in,
                                    const float* __restrict__ W_h,
                                    const float* __restrict__ W_out,
                                    unsigned short* __restrict__ ws) {
    const int TIN  = 8 * (WIN_EPL / 8);     // 81920
    const int TH   = 16 * (WH_EPB / 8);     // 524288
    const int TOUT = 8 * (WOUT_EPL / 8);    // 32768
    int t = blockIdx.x * blockDim.x + threadIdx.x;
    if (t >= TIN + TH + TOUT) return;
    v8s o;
    if (t < TIN + TH) {
        const float* src; int r;
        if (t < TIN) {
            int i = t / (WIN_EPL / 8); r = t - i * (WIN_EPL / 8);
            src = W_in + (size_t)i * WIN_EPL;
        } else {
            int u = t - TIN; int ij = u >> 15; r = u & 32767;
            src = W_h + (size_t)ij * WH_EPB;
        }
        int frag = r >> 6, lane = r & 63;
        int k0 = (frag >> 4) * 16 + (lane >> 5) * 8;
        int n  = (frag & 15) * 32 + (lane & 31);
#pragma unroll
        for (int j = 0; j < 8; ++j)
            o[j] = (short)f2b(src[(size_t)(k0 + j) * 512 + n]);
    } else {
        int u = t - TIN - TH;
        int i = u >> 12, r = u & 4095;
        const float* src = W_out + (size_t)i * WOUT_EPL;
        int frag = r >> 6, lane = r & 63;
        int k0 = (frag >> 2) * 32 + (lane >> 4) * 8;
        int n  = (frag & 3) * 16 + (lane & 15);
#pragma unroll
        for (int j = 0; j < 8; ++j)
            o[j] = (short)f2b(src[(size_t)(k0 + j) * 64 + n]);
    }
    *(v8s*)(ws + (size_t)t * 8) = o;
}

// ---------------------------------------------------------------------------
// 32x32x16 stage: h' = relu(A[64,KC*16] @ W[.,512] + bias) for one 32-col
// strip (ntile). Wave covers both 32-row tiles -> B frags read exactly once.
// 3-deep software pipeline on the B stream (vmcnt(2) steady state).
// ---------------------------------------------------------------------------
template<int KC, bool PACKED>
__device__ __forceinline__ void gemm32(
    const unsigned short* __restrict__ wpk,
    const float* __restrict__ wraw,
    const float* __restrict__ bias,
    const unsigned short* __restrict__ Abuf,
    unsigned short* __restrict__ Obuf,
    int ntile, int lane)
{
    const int l31 = lane & 31, half = lane >> 5;
    v16f acc0, acc1;
#pragma unroll
    for (int r = 0; r < 16; ++r) { acc0[r] = 0.f; acc1[r] = 0.f; }
    const int row0 = l31, row1 = 32 + l31;
    const int ab0 = row0 * 512, ab1 = row1 * 512;
    const int sz0 = sw3(row0), sz1 = sw3(row1);
    const unsigned short* bptr =
        PACKED ? wpk + (size_t)(ntile * 64 + lane) * 8 : (const unsigned short*)0;

    auto loadB = [&](int idx) -> v8s {
        if (idx >= KC) idx = KC - 1;     // clamped duplicate, harmless
        if constexpr (PACKED) {
            return *(const v8s*)(bptr + (size_t)idx * (16 * 512));
        } else {
            int n = ntile * 32 + l31;
            int k0 = idx * 16 + half * 8;
            v8s bb;
#pragma unroll
            for (int j = 0; j < 8; ++j)
                bb[j] = (short)f2b(wraw[(size_t)(k0 + j) * 512 + n]);
            return bb;
        }
    };
    auto step = [&](int kc, v8s bf) {
        const int cch = (kc * 2 + half) << 3;
        v8s a0 = *(const v8s*)(Abuf + ab0 + (cch ^ sz0));
        v8s a1 = *(const v8s*)(Abuf + ab1 + (cch ^ sz1));
        acc0 = __builtin_amdgcn_mfma_f32_32x32x16_bf16(a0, bf, acc0, 0, 0, 0);
        acc1 = __builtin_amdgcn_mfma_f32_32x32x16_bf16(a1, bf, acc1, 0, 0, 0);
    };

    v8s b0 = loadB(0), b1 = loadB(1), b2 = loadB(2);
    int kc = 0;
#pragma unroll 1
    for (; kc + 2 < KC; kc += 3) {
        step(kc + 0, b0); b0 = loadB(kc + 3);
        step(kc + 1, b1); b1 = loadB(kc + 4);
        step(kc + 2, b2); b2 = loadB(kc + 5);
    }
    if (kc < KC)     step(kc + 0, b0);
    if (kc + 1 < KC) step(kc + 1, b1);

    // epilogue: col = ntile*32 + (lane&31); row = (reg&3)+8*(reg>>2)+4*half
    const int n = ntile * 32 + l31;
    const float bv = bias[n];
    const int nch = (n >> 3) << 3, nlo = n & 7;
#pragma unroll
    for (int reg = 0; reg < 16; ++reg) {
        int row = (reg & 3) + 8 * (reg >> 2) + 4 * half;
        float v0 = acc0[reg] + bv; v0 = v0 > 0.f ? v0 : 0.f;
        Obuf[row * 512 + (nch ^ sw3(row)) + nlo] = f2b(v0);
        int rw1 = row + 32;
        float v1 = acc1[reg] + bv; v1 = v1 > 0.f ? v1 : 0.f;
        Obuf[rw1 * 512 + (nch ^ sw3(rw1)) + nlo] = f2b(v1);
    }
}

__device__ __forceinline__ v4f mfma16(v8s a, v8s b, v4f c) {
    return __builtin_amdgcn_mfma_f32_16x16x32_bf16(a, b, c, 0, 0, 0);
}

// 16x16x32 output stage (G3): p[16 rows x 16 cols] = h @ W_out + b_out, fp32.
// Same 3-deep B pipeline.
template<bool PACKED>
__device__ __forceinline__ void gemm16_out(
    const unsigned short* __restrict__ wpk,
    const float* __restrict__ wraw,
    const float* __restrict__ bias,
    const unsigned short* __restrict__ Abuf,
    float* __restrict__ Pbuf,
    int mtb, int ntb, int lane)
{
    const int quad = lane >> 4, l15 = lane & 15;
    v4f acc; acc[0] = acc[1] = acc[2] = acc[3] = 0.f;
    const int row = mtb * 16 + l15;
    const int ab = row * 512, sz = sw3(row);
    const unsigned short* bptr =
        PACKED ? wpk + (size_t)(ntb * 64 + lane) * 8 : (const unsigned short*)0;
    constexpr int KC = 16;

    auto loadB = [&](int idx) -> v8s {
        if (idx >= KC) idx = KC - 1;
        if constexpr (PACKED) {
            return *(const v8s*)(bptr + (size_t)(idx * 4) * 512);
        } else {
            int k0 = idx * 32 + quad * 8;
            int n  = ntb * 16 + l15;
            v8s bb;
#pragma unroll
            for (int j = 0; j < 8; ++j)
                bb[j] = (short)f2b(wraw[(size_t)(k0 + j) * 64 + n]);
            return bb;
        }
    };
    auto step = [&](int kc, v8s bf) {
        v8s a = *(const v8s*)(Abuf + ab + ((((kc * 4 + quad) << 3)) ^ sz));
        acc = mfma16(a, bf, acc);
    };

    v8s b0 = loadB(0), b1 = loadB(1), b2 = loadB(2);
    int kc = 0;
#pragma unroll 1
    for (; kc + 2 < KC; kc += 3) {
        step(kc + 0, b0); b0 = loadB(kc + 3);
        step(kc + 1, b1); b1 = loadB(kc + 4);
        step(kc + 2, b2); b2 = loadB(kc + 5);
    }
    if (kc < KC)     step(kc + 0, b0);
    if (kc + 1 < KC) step(kc + 1, b1);

    const int n = ntb * 16 + l15;
    const float bv = bias[n];
#pragma unroll
    for (int r = 0; r < 4; ++r)
        Pbuf[(mtb * 16 + quad * 4 + r) * PST + n] = acc[r] + bv;
}

template<bool PACKED>
__global__ __launch_bounds__(1024) void flow_kernel(
    const float* __restrict__ inputs,
    const float* __restrict__ ctx,
    const float* __restrict__ W_in,  const float* __restrict__ b_in,
    const float* __restrict__ W_h,   const float* __restrict__ b_h,
    const float* __restrict__ W_out, const float* __restrict__ b_out,
    const int*   __restrict__ perms,
    const unsigned short* __restrict__ wpk,
    float* __restrict__ out)
{
    __shared__ __align__(16) unsigned short hbuf0[64 * 512];  // 65,536 B
    __shared__ __align__(16) unsigned short hbuf1[64 * 512];  // 65,536 B
    __shared__ __align__(16) float xbuf[64 * NF];             // 16,384 B
    __shared__ int permsh[NF];

    float* pbuf    = (float*)hbuf0;   // p (64 x 64 fp32, stride PST) after G3
    float* scratch = (float*)hbuf1;   // permutation scratch

    const int tid  = threadIdx.x;
    const int wave = tid >> 6;        // 0..15
    const int lane = tid & 63;
    const int trow = tid >> 4;        // 0..63 : row owned in elementwise phases
    const int tq   = tid & 15;        // 0..15 : 1/16th of that row
    const int row0 = blockIdx.x * 64;

    // ---- load + clip x tile (1024 float4 / 1024 threads = 1 each)
    {
        const float4* in4 = (const float4*)(inputs + (size_t)row0 * NF);
        float4 v = in4[tid];
        v.x = fminf(fmaxf(v.x, -1.f), 1.f);
        v.y = fminf(fmaxf(v.y, -1.f), 1.f);
        v.z = fminf(fmaxf(v.z, -1.f), 1.f);
        v.w = fminf(fmaxf(v.w, -1.f), 1.f);
        ((float4*)xbuf)[tid] = v;
    }
    float ld_acc = 0.f;
    __syncthreads();

#pragma unroll 1
    for (int i = 0; i < NL; ++i) {
        const int par = i & 1;        // t_idx parity (even layer -> even cols)
        const int idp = par ^ 1;      // id_idx parity

        // ---- stage A0 = [id_split(32) | context(128)] bf16 into hbuf0
        {
            const int s3 = sw3(trow);
            unsigned short* hrow = hbuf0 + trow * 512;

            const float* crow = ctx + (size_t)(row0 + trow) * NCTX + tq * 8;
            float4 f0 = ((const float4*)crow)[0];
            float4 f1 = ((const float4*)crow)[1];
            v8s ck;
            ck[0] = (short)f2b(f0.x); ck[1] = (short)f2b(f0.y);
            ck[2] = (short)f2b(f0.z); ck[3] = (short)f2b(f0.w);
            ck[4] = (short)f2b(f1.x); ck[5] = (short)f2b(f1.y);
            ck[6] = (short)f2b(f1.z); ck[7] = (short)f2b(f1.w);
            *(v8s*)(hrow + (((4 + tq) << 3) ^ s3)) = ck;

            if (tq < 4) {
                v8s idv;
#pragma unroll
                for (int j = 0; j < 8; ++j)
                    idv[j] = (short)f2b(xbuf[trow * NF + 2 * (tq * 8 + j) + idp]);
                *(v8s*)(hrow + ((tq << 3) ^ s3)) = idv;
            }
        }
        __syncthreads();

        // ---- G0: h = relu([id|ctx] @ W_in + b_in)   (K=160, N=512)
        gemm32<10, PACKED>(
            PACKED ? wpk + OFF_WIN + (size_t)i * WIN_EPL : (const unsigned short*)0,
            W_in + (size_t)i * WIN_EPL, b_in + i * 512,
            hbuf0, hbuf1, wave, lane);
        __syncthreads();
        // ---- G1
        gemm32<32, PACKED>(
            PACKED ? wpk + OFF_WH + (size_t)(i * 2 + 0) * WH_EPB : (const unsigned short*)0,
            W_h + (size_t)(i * 2 + 0) * WH_EPB, b_h + (i * 2 + 0) * 512,
            hbuf1, hbuf0, wave, lane);
        __syncthreads();
        // ---- G2
        gemm32<32, PACKED>(
            PACKED ? wpk + OFF_WH + (size_t)(i * 2 + 1) * WH_EPB : (const unsigned short*)0,
            W_h + (size_t)(i * 2 + 1) * WH_EPB, b_h + (i * 2 + 1) * 512,
            hbuf0, hbuf1, wave, lane);
        __syncthreads();
        // ---- G3: p = h @ W_out + b_out  (N=64, fp32 into pbuf)
        //      16 waves x 1 tile: mtb = wave>>2, ntb = wave&3
        gemm16_out<PACKED>(
            PACKED ? wpk + OFF_WOUT + (size_t)i * WOUT_EPL : (const unsigned short*)0,
            W_out + (size_t)i * WOUT_EPL, b_out + i * 64,
            hbuf1, pbuf, wave >> 2, wave & 3, lane);
        __syncthreads();

        // ---- coupling: shift = p[:, :32]; scale = sigmoid(p[:,32:]+2)+1e-3
        {
#pragma unroll
            for (int j = 0; j < 2; ++j) {
                int sc = tq * 2 + j;
                float shiftv = pbuf[trow * PST + sc];
                float z = pbuf[trow * PST + 32 + sc] + 2.0f;
                float s = 1.0f / (1.0f + __expf(-z)) + 0.001f;
                int tc = 2 * sc + par;
                xbuf[trow * NF + tc] = xbuf[trow * NF + tc] * s + shiftv;
                ld_acc += __logf(s);
            }
        }
        __syncthreads();

        // ---- permutation: x = x[:, perm[i]]
        if (i < NL - 1) {
            ((float4*)scratch)[tid] = ((float4*)xbuf)[tid];
            if (tid < NF) permsh[tid] = perms[i * NF + tid];
            __syncthreads();
#pragma unroll
            for (int j = 0; j < 4; ++j) {
                int c = tq * 4 + j;
                xbuf[trow * NF + c] = scratch[trow * NF + permsh[c]];
            }
            __syncthreads();
        }
    }

    // ---- outputs: clip(x) then logdet
    {
        float4 v = ((float4*)xbuf)[tid];
        v.x = fminf(fmaxf(v.x, -1.f), 1.f);
        v.y = fminf(fmaxf(v.y, -1.f), 1.f);
        v.z = fminf(fmaxf(v.z, -1.f), 1.f);
        v.w = fminf(fmaxf(v.w, -1.f), 1.f);
        ((float4*)(out + (size_t)row0 * NF))[tid] = v;
    }
    // reduce 16 partials per row (lanes 16r..16r+15 contiguous in a wave)
    ld_acc += __shfl_down(ld_acc, 1);
    ld_acc += __shfl_down(ld_acc, 2);
    ld_acc += __shfl_down(ld_acc, 4);
    ld_acc += __shfl_down(ld_acc, 8);
    if (tq == 0) out[(size_t)BATCH * NF + row0 + trow] = ld_acc;
}

extern "C" void kernel_launch(void* const* d_in, const int* in_sizes, int n_in,
                              void* d_out, int out_size, void* d_ws, size_t ws_size,
                              hipStream_t stream) {
    const float* inputs  = (const float*)d_in[0];
    const float* context = (const float*)d_in[1];
    const float* W_in    = (const float*)d_in[2];
    const float* b_in    = (const float*)d_in[3];
    const float* W_h     = (const float*)d_in[4];
    const float* b_h     = (const float*)d_in[5];
    const float* W_out   = (const float*)d_in[6];
    const float* b_out   = (const float*)d_in[7];
    const int*   perms   = (const int*)d_in[8];
    float* out = (float*)d_out;

    if (ws_size >= (size_t)NEED_WS) {
        unsigned short* ws = (unsigned short*)d_ws;
        const int total_threads = (int)(TOT_PACK_ELEMS / 8);    // 638976
        pack_weights_kernel<<<(total_threads + 255) / 256, 256, 0, stream>>>(
            W_in, W_h, W_out, ws);
        flow_kernel<true><<<256, 1024, 0, stream>>>(
            inputs, context, W_in, b_in, W_h, b_h, W_out, b_out, perms, ws, out);
    } else {
        flow_kernel<false><<<256, 1024, 0, stream>>>(
            inputs, context, W_in, b_in, W_h, b_h, W_out, b_out, perms,
            (const unsigned short*)0, out);
    }
}